// Round 1
// baseline (302.508 us; speedup 1.0000x reference)
//
#include <hip/hip_runtime.h>

// GCN_84499186582104 — fully fused, one thread per (batch, node).
// B=131072, V=8, NFEAT=32, NHID1=16, NHID12=8, NCLASS=2.
// R8 (base = R7, ~96us kernel / 271us harness):
//   Theory: LDS-pipe-bound (~192 ds_read_b128/wave of weight broadcasts) +
//   occupancy capped at 8 blocks/CU by 20 KiB LDS.
//   - Weights moved to a 4KB d_ws block (prep kernel transposes wbT/wgT,
//     copies w1/w2/biases/wf/bf). All weight reads are uniform, constant
//     offsets -> s_load / cached broadcast on the SMEM/VMEM pipes; the LDS
//     pipe only carries the cross-lane exchanges (~125 ops/wave).
//   - LDS shrunk 20352B -> 8960B (2240 floats): per-slot region 140 floats.
//     * x staged in two phases (features 0..15 then 16..31) into the same
//       128-float cells; x loads split 4+4 per thread (thread (sl,v) loads
//       chunk v&3 of nodes (v&4)+0..3) so no lane holds 8 float4 long.
//     * g1 exchanged in two 64-float halves; g2/pool reuse the same cells.
//     * pool: interleaved (Y,h2) float2 layout + type[8] at offset 128.
//   - Slot stride 140 floats (35 groups, odd mod 8): all exchange patterns
//     verified <=2-way; broadcast row reads conflict-free.
//   - No __syncthreads left; blocks = 2 independent waves.
//   Occupancy cap 8 -> 16 blocks/CU (32 waves). VGPR target <= ~72.

#define SLOTS 16      // batches per block
#define NTHREADS 128  // 8 threads per batch; slots never span a wave

// d_ws weight layout (floats)
#define WBT 0      // wbT[c*8+o]                  (256)
#define W1O 256    // w1[c*16+j] natural          (512)
#define W2O 768    // w2[j*8+n]  natural          (128)
#define WGT 896    // wgT[n*8+o]                  (64)
#define BBO 960    // bb (8)
#define B1O 968    // b1 (16)
#define B2O 984    // b2 (8)
#define WFO 992    // wf (16)
#define BFO 1008   // bf (2)
#define NWS 1010

typedef float v2f __attribute__((ext_vector_type(2)));
typedef float4 __attribute__((aligned(4))) f4u;   // dword-aligned float4 load

__device__ __forceinline__ float grp_sum8(float x) {
    x += __shfl_xor(x, 1);
    x += __shfl_xor(x, 2);
    x += __shfl_xor(x, 4);
    return x;
}
__device__ __forceinline__ void wavefence() { __builtin_amdgcn_wave_barrier(); }
__device__ __forceinline__ v2f mkv(float a, float b) { v2f r; r.x = a; r.y = b; return r; }

__global__ void gcn_prep(const float* __restrict__ wb, const float* __restrict__ bb,
                         const float* __restrict__ w1, const float* __restrict__ b1,
                         const float* __restrict__ w2, const float* __restrict__ b2,
                         const float* __restrict__ wg, const float* __restrict__ wf,
                         const float* __restrict__ bf, float* __restrict__ ws)
{
    const int t = threadIdx.x;
    for (int i = t; i < 256; i += 256) ws[WBT + (i & 31) * 8 + (i >> 5)] = wb[i];
    for (int i = t; i < 512; i += 256) ws[W1O + i] = w1[i];
    if (t < 128) ws[W2O + t] = w2[t];
    if (t < 64)  ws[WGT + (t & 7) * 8 + (t >> 3)] = wg[t];
    if (t < 8)   ws[BBO + t] = bb[t];
    if (t < 16)  ws[B1O + t] = b1[t];
    if (t < 8)   ws[B2O + t] = b2[t];
    if (t < 16)  ws[WFO + t] = wf[t];
    if (t < 2)   ws[BFO + t] = bf[t];
}

// LDS float layout (per-wave region of 1120 floats; slot stride 140):
//   SB = lds + (slot>>3)*1120 + sl*140, sl = slot&7
//   xstage cells:  SB + n*16 + ((c + 2*sl + n)&3)*4   (phase-local chunk c)
//   A (Fk/S):      SB + 64 + o*8 + w
//   g-rows:        SB + r*8            (g1 halves, then g2)
//   pool:          SB + vp*16 + o*2 (Y), +1 (h2);  type at SB + 128 + vp

// One K-step of the fused Fk/g1 loop: kk = phase-local chunk (0..3),
// cb = global feature base for this chunk.
#define KSTEP(kk, cb) { \
    const float4 qk = *(const float4*)(SB + v * 16 + ((((kk) + 2 * sl + v) & 3) << 2)); \
    const float f[4] = { qk.x, qk.y, qk.z, qk.w }; \
    _Pragma("unroll") \
    for (int u = 0; u < 4; ++u) { \
        const int c = (cb) + u; \
        const v2f f2 = mkv(f[u], f[u]); \
        const float4* wbc = (const float4*)(wsW + WBT + c * 8); \
        const float4 wa = wbc[0], wbq = wbc[1]; \
        Fk2[0] = __builtin_elementwise_fma(f2, mkv(wa.x,  wa.y),  Fk2[0]); \
        Fk2[1] = __builtin_elementwise_fma(f2, mkv(wa.z,  wa.w),  Fk2[1]); \
        Fk2[2] = __builtin_elementwise_fma(f2, mkv(wbq.x, wbq.y), Fk2[2]); \
        Fk2[3] = __builtin_elementwise_fma(f2, mkv(wbq.z, wbq.w), Fk2[3]); \
        const float4* w1c = (const float4*)(wsW + W1O + c * 16); \
        const float4 wc0 = w1c[0], wc1 = w1c[1], wc2 = w1c[2], wc3 = w1c[3]; \
        g12[0] = __builtin_elementwise_fma(f2, mkv(wc0.x, wc0.y), g12[0]); \
        g12[1] = __builtin_elementwise_fma(f2, mkv(wc0.z, wc0.w), g12[1]); \
        g12[2] = __builtin_elementwise_fma(f2, mkv(wc1.x, wc1.y), g12[2]); \
        g12[3] = __builtin_elementwise_fma(f2, mkv(wc1.z, wc1.w), g12[3]); \
        g12[4] = __builtin_elementwise_fma(f2, mkv(wc2.x, wc2.y), g12[4]); \
        g12[5] = __builtin_elementwise_fma(f2, mkv(wc2.z, wc2.w), g12[5]); \
        g12[6] = __builtin_elementwise_fma(f2, mkv(wc3.x, wc3.y), g12[6]); \
        g12[7] = __builtin_elementwise_fma(f2, mkv(wc3.z, wc3.w), g12[7]); \
    } }

__global__ __launch_bounds__(NTHREADS, 6)
void gcn_fused(const float* __restrict__ x,
               const float* __restrict__ adj,
               const float* __restrict__ edge,
               const float* __restrict__ wsW,
               float* __restrict__ out, int nGroups)
{
    __shared__ __align__(16) float lds[2240];   // 8960 B -> 16 blocks/CU (thread cap)

    const int tid  = threadIdx.x;
    const int slot = tid >> 3;
    const int v    = tid & 7;
    const int sl   = slot & 7;
    float* SB = &lds[(slot >> 3) * 1120 + sl * 140];
    float* A  = SB + 64;

    long long bb_ = (long long)blockIdx.x * SLOTS + slot;
    if (bb_ >= (long long)nGroups * SLOTS) bb_ = (long long)nGroups * SLOTS - 1;
    const size_t b = (size_t)bb_;

    // ---- global loads: phase-A x first, then adj/edge/type (stay in flight) ----
    const float* xb = x + b * 264;
    const int nb = v & 4;           // this lane covers nodes nb..nb+3
    const int cl = v & 3;           // ... feature chunk cl of each
    float4 xa[4];
#pragma unroll
    for (int i = 0; i < 4; ++i)
        xa[i] = *(const f4u*)(xb + (nb + i) * 33 + 1 + cl * 4);

    const float4* ar = (const float4*)(adj  + b * 64 + (size_t)v * 8);
    const float4* er = (const float4*)(edge + b * 64 + (size_t)v * 8);
    const float4 a0 = ar[0], a1 = ar[1];
    const float4 e0 = er[0], e1 = er[1];
    const float type = xb[v * 33];

    // ---- stage phase A (features 0..15 of all 8 nodes), issue phase-B loads ----
#pragma unroll
    for (int i = 0; i < 4; ++i) {
        const int n = nb + i;
        *(float4*)(SB + n * 16 + (((cl + 2 * sl + n) & 3) << 2)) = xa[i];
    }
    float4 xc[4];
#pragma unroll
    for (int i = 0; i < 4; ++i)
        xc[i] = *(const f4u*)(xb + (nb + i) * 33 + 17 + cl * 4);
    wavefence();

    // ---- Fk (output-paired) + g1 (output-paired), packed fp32 ----
    v2f Fk2[4];
    {
        const v2f* bbp = (const v2f*)&wsW[BBO];
#pragma unroll
        for (int p = 0; p < 4; ++p) Fk2[p] = bbp[p];
    }
    v2f g12[8];
#pragma unroll
    for (int p = 0; p < 8; ++p) g12[p] = mkv(0.f, 0.f);

    KSTEP(0, 0) KSTEP(1, 4) KSTEP(2, 8) KSTEP(3, 12)
    wavefence();                    // phase-A reads done -> restage same cells
#pragma unroll
    for (int i = 0; i < 4; ++i) {
        const int n = nb + i;
        *(float4*)(SB + n * 16 + (((cl + 2 * sl + n) & 3) << 2)) = xc[i];
    }
    wavefence();
    KSTEP(0, 16) KSTEP(1, 20) KSTEP(2, 24) KSTEP(3, 28)
    wavefence();                    // stage dead -> A / g-rows may overwrite

    // ---- share Fk (column v -> A) and g1 half 0 (row v -> g-rows) ----
#pragma unroll
    for (int p = 0; p < 4; ++p) {
        A[(2 * p)     * 8 + v] = Fk2[p].x;
        A[(2 * p + 1) * 8 + v] = Fk2[p].y;
    }
    {
        float4* gp = (float4*)(SB + v * 8);
        gp[0] = make_float4(g12[0].x, g12[0].y, g12[1].x, g12[1].y);
        gp[1] = make_float4(g12[2].x, g12[2].y, g12[3].x, g12[3].y);
    }
    wavefence();

    // ---- M[o][v] = dot(Fk row o, Fk column v); softmax over o ----
    float M[8];
#pragma unroll
    for (int o = 0; o < 8; ++o) {
        const float4* fr = (const float4*)(A + o * 8);
        const float4 r0 = fr[0], r1 = fr[1];
        v2f acc = mkv(0.f, 0.f);
        acc = __builtin_elementwise_fma(mkv(r0.x, r0.y), Fk2[0], acc);
        acc = __builtin_elementwise_fma(mkv(r0.z, r0.w), Fk2[1], acc);
        acc = __builtin_elementwise_fma(mkv(r1.x, r1.y), Fk2[2], acc);
        acc = __builtin_elementwise_fma(mkv(r1.z, r1.w), Fk2[3], acc);
        M[o] = acc.x + acc.y;
    }
    wavefence();
    float mx = M[0];
#pragma unroll
    for (int o = 1; o < 8; ++o) mx = fmaxf(mx, M[o]);
    float ssum = 0.f;
#pragma unroll
    for (int o = 0; o < 8; ++o) { M[o] = __expf(M[o] - mx); ssum += M[o]; }
    const float sinv = 1.f / ssum;
#pragma unroll
    for (int o = 0; o < 8; ++o) A[o * 8 + v] = M[o] * sinv;   // S column
    wavefence();

    // ---- W row (packed): W = adj * (S + edge) ----
    const float4* sr = (const float4*)(A + v * 8);
    const float4 s0 = sr[0], s1 = sr[1];
    v2f W2[4];
    W2[0] = mkv(a0.x, a0.y) * (mkv(s0.x, s0.y) + mkv(e0.x, e0.y));
    W2[1] = mkv(a0.z, a0.w) * (mkv(s0.z, s0.w) + mkv(e0.z, e0.w));
    W2[2] = mkv(a1.x, a1.y) * (mkv(s1.x, s1.y) + mkv(e1.x, e1.y));
    W2[3] = mkv(a1.z, a1.w) * (mkv(s1.z, s1.w) + mkv(e1.z, e1.w));

    // ---- layer 1: h = leaky(W @ g1 + b1), g1 consumed in two halves ----
    v2f m1[8];
#pragma unroll
    for (int p = 0; p < 8; ++p) m1[p] = mkv(0.f, 0.f);
#pragma unroll
    for (int w = 0; w < 8; ++w) {                 // half 0: g1[:,0:8]
        const float wv = (w & 1) ? W2[w >> 1].y : W2[w >> 1].x;
        const v2f f2 = mkv(wv, wv);
        const float4* gp = (const float4*)(SB + w * 8);
        const float4 q0 = gp[0], q1 = gp[1];
        m1[0] = __builtin_elementwise_fma(f2, mkv(q0.x, q0.y), m1[0]);
        m1[1] = __builtin_elementwise_fma(f2, mkv(q0.z, q0.w), m1[1]);
        m1[2] = __builtin_elementwise_fma(f2, mkv(q1.x, q1.y), m1[2]);
        m1[3] = __builtin_elementwise_fma(f2, mkv(q1.z, q1.w), m1[3]);
    }
    wavefence();                                  // half-0 reads done
    {
        float4* gp = (float4*)(SB + v * 8);       // publish half 1: g1[:,8:16]
        gp[0] = make_float4(g12[4].x, g12[4].y, g12[5].x, g12[5].y);
        gp[1] = make_float4(g12[6].x, g12[6].y, g12[7].x, g12[7].y);
    }
    wavefence();
#pragma unroll
    for (int w = 0; w < 8; ++w) {                 // half 1
        const float wv = (w & 1) ? W2[w >> 1].y : W2[w >> 1].x;
        const v2f f2 = mkv(wv, wv);
        const float4* gp = (const float4*)(SB + w * 8);
        const float4 q0 = gp[0], q1 = gp[1];
        m1[4] = __builtin_elementwise_fma(f2, mkv(q0.x, q0.y), m1[4]);
        m1[5] = __builtin_elementwise_fma(f2, mkv(q0.z, q0.w), m1[5]);
        m1[6] = __builtin_elementwise_fma(f2, mkv(q1.x, q1.y), m1[6]);
        m1[7] = __builtin_elementwise_fma(f2, mkv(q1.z, q1.w), m1[7]);
    }
    v2f h[8];
    {
        const v2f* b1p = (const v2f*)&wsW[B1O];
        const v2f k01 = mkv(0.01f, 0.01f);
#pragma unroll
        for (int p = 0; p < 8; ++p) {
            const v2f t = m1[p] + b1p[p];
            h[p] = __builtin_elementwise_max(t, t * k01);   // leaky
        }
    }

    // ---- g2 row: g2[n] = dot(h, w2[:,n]), packed over n ----
    v2f g22[4];
#pragma unroll
    for (int p = 0; p < 4; ++p) g22[p] = mkv(0.f, 0.f);
#pragma unroll
    for (int j = 0; j < 16; ++j) {
        const float hv = (j & 1) ? h[j >> 1].y : h[j >> 1].x;
        const v2f f2 = mkv(hv, hv);
        const float4* w2r = (const float4*)(wsW + W2O + j * 8);
        const float4 r0 = w2r[0], r1 = w2r[1];
        g22[0] = __builtin_elementwise_fma(f2, mkv(r0.x, r0.y), g22[0]);
        g22[1] = __builtin_elementwise_fma(f2, mkv(r0.z, r0.w), g22[1]);
        g22[2] = __builtin_elementwise_fma(f2, mkv(r1.x, r1.y), g22[2]);
        g22[3] = __builtin_elementwise_fma(f2, mkv(r1.z, r1.w), g22[3]);
    }
    wavefence();   // g1 half-1 reads done -> overwrite g-rows with g2
    {
        float4* gp = (float4*)(SB + v * 8);
        gp[0] = make_float4(g22[0].x, g22[0].y, g22[1].x, g22[1].y);
        gp[1] = make_float4(g22[2].x, g22[2].y, g22[3].x, g22[3].y);
    }
    wavefence();

    // ---- layer 2: h2 = leaky(W @ g2 + b2), packed ----
    v2f m2[4];
#pragma unroll
    for (int p = 0; p < 4; ++p) m2[p] = mkv(0.f, 0.f);
#pragma unroll
    for (int w = 0; w < 8; ++w) {
        const float wv = (w & 1) ? W2[w >> 1].y : W2[w >> 1].x;
        const v2f f2 = mkv(wv, wv);
        const float4* gp = (const float4*)(SB + w * 8);
        const float4 q0 = gp[0], q1 = gp[1];
        m2[0] = __builtin_elementwise_fma(f2, mkv(q0.x, q0.y), m2[0]);
        m2[1] = __builtin_elementwise_fma(f2, mkv(q0.z, q0.w), m2[1]);
        m2[2] = __builtin_elementwise_fma(f2, mkv(q1.x, q1.y), m2[2]);
        m2[3] = __builtin_elementwise_fma(f2, mkv(q1.z, q1.w), m2[3]);
    }
    v2f h2[4];
    {
        const v2f* b2p = (const v2f*)&wsW[B2O];
        const v2f k01 = mkv(0.01f, 0.01f);
#pragma unroll
        for (int p = 0; p < 4; ++p) {
            const v2f t = m2[p] + b2p[p];
            h2[p] = __builtin_elementwise_max(t, t * k01);
        }
    }

    // ---- gate-logit row: Y[o] = dot(h2, wg[o,:]), packed over o via wgT ----
    v2f Y2[4];
#pragma unroll
    for (int p = 0; p < 4; ++p) Y2[p] = mkv(0.f, 0.f);
#pragma unroll
    for (int n = 0; n < 8; ++n) {
        const float hv = (n & 1) ? h2[n >> 1].y : h2[n >> 1].x;
        const v2f f2 = mkv(hv, hv);
        const float4* wgr = (const float4*)(wsW + WGT + n * 8);
        const float4 r0 = wgr[0], r1 = wgr[1];
        Y2[0] = __builtin_elementwise_fma(f2, mkv(r0.x, r0.y), Y2[0]);
        Y2[1] = __builtin_elementwise_fma(f2, mkv(r0.z, r0.w), Y2[1]);
        Y2[2] = __builtin_elementwise_fma(f2, mkv(r1.x, r1.y), Y2[2]);
        Y2[3] = __builtin_elementwise_fma(f2, mkv(r1.z, r1.w), Y2[3]);
    }
    wavefence();   // g2 reads done -> overwrite with pool layout
    {
        // interleaved (Y, h2) pairs: float4 j = (Y[2j], h2[2j], Y[2j+1], h2[2j+1])
        float4* pp = (float4*)(SB + v * 16);
        pp[0] = make_float4(Y2[0].x, h2[0].x, Y2[0].y, h2[0].y);
        pp[1] = make_float4(Y2[1].x, h2[1].x, Y2[1].y, h2[1].y);
        pp[2] = make_float4(Y2[2].x, h2[2].x, Y2[2].y, h2[2].y);
        pp[3] = make_float4(Y2[3].x, h2[3].x, Y2[3].y, h2[3].y);
        SB[128 + v] = type;
    }
    wavefence();

    // ---- attention pooling: thread handles gate-row o = v.
    // bg[o] constant along softmax axis -> drops out; masked rows logit 0.
    const int o = v;
    float yc[8], hc[8], ty[8];
#pragma unroll
    for (int vp = 0; vp < 8; ++vp) {
        const float2 q = *(const float2*)(SB + vp * 16 + o * 2);
        yc[vp] = q.x;
        hc[vp] = q.y;
        ty[vp] = SB[128 + vp];
    }
    float xp = 0.f;
#pragma unroll
    for (int t = 0; t < 2; ++t) {
        const float tv = (float)t;
        float l[8];
        float lmx = -1e30f;
#pragma unroll
        for (int vp = 0; vp < 8; ++vp) {
            l[vp] = (ty[vp] == tv) ? yc[vp] : 0.f;
            lmx = fmaxf(lmx, l[vp]);
        }
        float esum = 0.f, num = 0.f;
#pragma unroll
        for (int vp = 0; vp < 8; ++vp) {
            const float e = __expf(l[vp] - lmx);
            esum += e;
            num  += (ty[vp] == tv) ? e * hc[vp] : 0.f;
        }
        xp += 0.5f * num / esum;
    }

    // ---- classifier ----
    const float y0 = grp_sum8(xp * wsW[WFO + o]);
    const float y1 = grp_sum8(xp * wsW[WFO + 8 + o]);
    if (v == 0) {
        float2* op = (float2*)(out + b * 2);
        *op = make_float2(y0 + wsW[BFO], y1 + wsW[BFO + 1]);
    }
}

extern "C" void kernel_launch(void* const* d_in, const int* in_sizes, int n_in,
                              void* d_out, int out_size, void* d_ws, size_t ws_size,
                              hipStream_t stream) {
    const float* x    = (const float*)d_in[0];
    const float* adj  = (const float*)d_in[1];
    const float* edge = (const float*)d_in[2];
    // d_in[3]=wa, d_in[4]=ba unused by the reference.
    const float* wb   = (const float*)d_in[5];
    const float* bb   = (const float*)d_in[6];
    const float* w1   = (const float*)d_in[7];
    const float* b1   = (const float*)d_in[8];
    const float* w2   = (const float*)d_in[9];
    const float* b2   = (const float*)d_in[10];
    const float* wg   = (const float*)d_in[11];
    // d_in[12]=bg drops out of the softmax (constant along the node axis).
    const float* wf   = (const float*)d_in[13];
    const float* bf   = (const float*)d_in[14];
    float* out = (float*)d_out;
    float* ws  = (float*)d_ws;

    const int Btot    = in_sizes[0] / 264;            // B = 131072
    const int nGroups = (Btot + SLOTS - 1) / SLOTS;   // 8192

    gcn_prep<<<1, 256, 0, stream>>>(wb, bb, w1, b1, w2, b2, wg, wf, bf, ws);
    gcn_fused<<<nGroups, NTHREADS, 0, stream>>>(x, adj, edge, ws, out, nGroups);
}

// Round 2
// 275.241 us; speedup vs baseline: 1.0991x; 1.0991x over previous
//
#include <hip/hip_runtime.h>

// GCN_84499186582104 — fully fused, one thread per (batch, node).
// B=131072, V=8, NFEAT=32, NHID1=16, NHID12=8, NCLASS=2.
// R9 (base = R8, 115us kernel — regression from R7's 96us):
//   Post-mortem of R8: WRITE_SIZE 1MB->29.7MB + VGPR 52->40 = scratch
//   spills from __launch_bounds__(128,6) (cap 85 VGPR < ~100 live in
//   KSTEP). Spill dirty lines also evicted the 205MB input set from the
//   256MB L3 (FETCH 100->205MB, zero inter-dispatch reuse); duration
//   tracked HBM traffic exactly. Bank conflicts UP (6.8M->10.4M): the
//   (c+2sl+v)&3 stage swizzle is lumpy for b128 (v&3 repeats on even v).
//   Fixes, keeping R8's wins (weights in d_ws, 9216B LDS):
//   - __launch_bounds__(128,4): VGPR cap 128, no spills (R7-proven).
//   - xstage swizzle cell=(c+(n>>1)+sl)&3: quad-start 3sl+4(v&1)+cell
//     covers all 8 b128 quad-starts exactly once per slot -> uniform
//     8/bank on reads AND the 4 staging stores (enumerated).
//   All other exchange patterns verified <=2-way (free) or uniform.

#define SLOTS 16      // batches per block
#define NTHREADS 128  // 8 threads per batch; slots never span a wave

// d_ws weight layout (floats)
#define WBT 0      // wbT[c*8+o]                  (256)
#define W1O 256    // w1[c*16+j] natural          (512)
#define W2O 768    // w2[j*8+n]  natural          (128)
#define WGT 896    // wgT[n*8+o]                  (64)
#define BBO 960    // bb (8)
#define B1O 968    // b1 (16)
#define B2O 984    // b2 (8)
#define WFO 992    // wf (16)
#define BFO 1008   // bf (2)
#define NWS 1010

typedef float v2f __attribute__((ext_vector_type(2)));
typedef float4 __attribute__((aligned(4))) f4u;   // dword-aligned float4 load

__device__ __forceinline__ float grp_sum8(float x) {
    x += __shfl_xor(x, 1);
    x += __shfl_xor(x, 2);
    x += __shfl_xor(x, 4);
    return x;
}
__device__ __forceinline__ void wavefence() { __builtin_amdgcn_wave_barrier(); }
__device__ __forceinline__ v2f mkv(float a, float b) { v2f r; r.x = a; r.y = b; return r; }

__global__ void gcn_prep(const float* __restrict__ wb, const float* __restrict__ bb,
                         const float* __restrict__ w1, const float* __restrict__ b1,
                         const float* __restrict__ w2, const float* __restrict__ b2,
                         const float* __restrict__ wg, const float* __restrict__ wf,
                         const float* __restrict__ bf, float* __restrict__ ws)
{
    const int t = threadIdx.x;
    for (int i = t; i < 256; i += 256) ws[WBT + (i & 31) * 8 + (i >> 5)] = wb[i];
    for (int i = t; i < 512; i += 256) ws[W1O + i] = w1[i];
    if (t < 128) ws[W2O + t] = w2[t];
    if (t < 64)  ws[WGT + (t & 7) * 8 + (t >> 3)] = wg[t];
    if (t < 8)   ws[BBO + t] = bb[t];
    if (t < 16)  ws[B1O + t] = b1[t];
    if (t < 8)   ws[B2O + t] = b2[t];
    if (t < 16)  ws[WFO + t] = wf[t];
    if (t < 2)   ws[BFO + t] = bf[t];
}

// LDS float layout (per-wave region of 1120 floats; slot stride 140):
//   SB = lds + (slot>>3)*1120 + sl*140, sl = slot&7
//   xstage cells:  SB + n*16 + ((c + (n>>1) + sl)&3)*4  (phase-local chunk c)
//   A (Fk/S):      SB + 64 + o*8 + w
//   g-rows:        SB + r*8            (g1 halves, then g2)
//   pool:          SB + vp*16 + o*2 (Y), +1 (h2);  type at SB + 128 + vp

// One K-step of the fused Fk/g1 loop: kk = phase-local chunk (0..3),
// cb = global feature base for this chunk.
#define KSTEP(kk, cb) { \
    const float4 qk = *(const float4*)(SB + v * 16 + ((((kk) + (v >> 1) + sl) & 3) << 2)); \
    const float f[4] = { qk.x, qk.y, qk.z, qk.w }; \
    _Pragma("unroll") \
    for (int u = 0; u < 4; ++u) { \
        const int c = (cb) + u; \
        const v2f f2 = mkv(f[u], f[u]); \
        const float4* wbc = (const float4*)(wsW + WBT + c * 8); \
        const float4 wa = wbc[0], wbq = wbc[1]; \
        Fk2[0] = __builtin_elementwise_fma(f2, mkv(wa.x,  wa.y),  Fk2[0]); \
        Fk2[1] = __builtin_elementwise_fma(f2, mkv(wa.z,  wa.w),  Fk2[1]); \
        Fk2[2] = __builtin_elementwise_fma(f2, mkv(wbq.x, wbq.y), Fk2[2]); \
        Fk2[3] = __builtin_elementwise_fma(f2, mkv(wbq.z, wbq.w), Fk2[3]); \
        const float4* w1c = (const float4*)(wsW + W1O + c * 16); \
        const float4 wc0 = w1c[0], wc1 = w1c[1], wc2 = w1c[2], wc3 = w1c[3]; \
        g12[0] = __builtin_elementwise_fma(f2, mkv(wc0.x, wc0.y), g12[0]); \
        g12[1] = __builtin_elementwise_fma(f2, mkv(wc0.z, wc0.w), g12[1]); \
        g12[2] = __builtin_elementwise_fma(f2, mkv(wc1.x, wc1.y), g12[2]); \
        g12[3] = __builtin_elementwise_fma(f2, mkv(wc1.z, wc1.w), g12[3]); \
        g12[4] = __builtin_elementwise_fma(f2, mkv(wc2.x, wc2.y), g12[4]); \
        g12[5] = __builtin_elementwise_fma(f2, mkv(wc2.z, wc2.w), g12[5]); \
        g12[6] = __builtin_elementwise_fma(f2, mkv(wc3.x, wc3.y), g12[6]); \
        g12[7] = __builtin_elementwise_fma(f2, mkv(wc3.z, wc3.w), g12[7]); \
    } }

__global__ __launch_bounds__(NTHREADS, 4)
void gcn_fused(const float* __restrict__ x,
               const float* __restrict__ adj,
               const float* __restrict__ edge,
               const float* __restrict__ wsW,
               float* __restrict__ out, int nGroups)
{
    __shared__ __align__(16) float lds[2240];   // 8960 B

    const int tid  = threadIdx.x;
    const int slot = tid >> 3;
    const int v    = tid & 7;
    const int sl   = slot & 7;
    float* SB = &lds[(slot >> 3) * 1120 + sl * 140];
    float* A  = SB + 64;

    long long bb_ = (long long)blockIdx.x * SLOTS + slot;
    if (bb_ >= (long long)nGroups * SLOTS) bb_ = (long long)nGroups * SLOTS - 1;
    const size_t b = (size_t)bb_;

    // ---- global loads: phase-A x first, then adj/edge/type (stay in flight) ----
    const float* xb = x + b * 264;
    const int nb = v & 4;           // this lane covers nodes nb..nb+3
    const int cl = v & 3;           // ... feature chunk cl of each
    float4 xa[4];
#pragma unroll
    for (int i = 0; i < 4; ++i)
        xa[i] = *(const f4u*)(xb + (nb + i) * 33 + 1 + cl * 4);

    const float4* ar = (const float4*)(adj  + b * 64 + (size_t)v * 8);
    const float4* er = (const float4*)(edge + b * 64 + (size_t)v * 8);
    const float4 a0 = ar[0], a1 = ar[1];
    const float4 e0 = er[0], e1 = er[1];
    const float type = xb[v * 33];

    // ---- stage phase A (features 0..15 of all 8 nodes), issue phase-B loads ----
#pragma unroll
    for (int i = 0; i < 4; ++i) {
        const int n = nb + i;
        *(float4*)(SB + n * 16 + (((cl + (n >> 1) + sl) & 3) << 2)) = xa[i];
    }
    float4 xc[4];
#pragma unroll
    for (int i = 0; i < 4; ++i)
        xc[i] = *(const f4u*)(xb + (nb + i) * 33 + 17 + cl * 4);
    wavefence();

    // ---- Fk (output-paired) + g1 (output-paired), packed fp32 ----
    v2f Fk2[4];
    {
        const v2f* bbp = (const v2f*)&wsW[BBO];
#pragma unroll
        for (int p = 0; p < 4; ++p) Fk2[p] = bbp[p];
    }
    v2f g12[8];
#pragma unroll
    for (int p = 0; p < 8; ++p) g12[p] = mkv(0.f, 0.f);

    KSTEP(0, 0) KSTEP(1, 4) KSTEP(2, 8) KSTEP(3, 12)
    wavefence();                    // phase-A reads done -> restage same cells
#pragma unroll
    for (int i = 0; i < 4; ++i) {
        const int n = nb + i;
        *(float4*)(SB + n * 16 + (((cl + (n >> 1) + sl) & 3) << 2)) = xc[i];
    }
    wavefence();
    KSTEP(0, 16) KSTEP(1, 20) KSTEP(2, 24) KSTEP(3, 28)
    wavefence();                    // stage dead -> A / g-rows may overwrite

    // ---- share Fk (column v -> A) and g1 half 0 (row v -> g-rows) ----
#pragma unroll
    for (int p = 0; p < 4; ++p) {
        A[(2 * p)     * 8 + v] = Fk2[p].x;
        A[(2 * p + 1) * 8 + v] = Fk2[p].y;
    }
    {
        float4* gp = (float4*)(SB + v * 8);
        gp[0] = make_float4(g12[0].x, g12[0].y, g12[1].x, g12[1].y);
        gp[1] = make_float4(g12[2].x, g12[2].y, g12[3].x, g12[3].y);
    }
    wavefence();

    // ---- M[o][v] = dot(Fk row o, Fk column v); softmax over o ----
    float M[8];
#pragma unroll
    for (int o = 0; o < 8; ++o) {
        const float4* fr = (const float4*)(A + o * 8);
        const float4 r0 = fr[0], r1 = fr[1];
        v2f acc = mkv(0.f, 0.f);
        acc = __builtin_elementwise_fma(mkv(r0.x, r0.y), Fk2[0], acc);
        acc = __builtin_elementwise_fma(mkv(r0.z, r0.w), Fk2[1], acc);
        acc = __builtin_elementwise_fma(mkv(r1.x, r1.y), Fk2[2], acc);
        acc = __builtin_elementwise_fma(mkv(r1.z, r1.w), Fk2[3], acc);
        M[o] = acc.x + acc.y;
    }
    wavefence();
    float mx = M[0];
#pragma unroll
    for (int o = 1; o < 8; ++o) mx = fmaxf(mx, M[o]);
    float ssum = 0.f;
#pragma unroll
    for (int o = 0; o < 8; ++o) { M[o] = __expf(M[o] - mx); ssum += M[o]; }
    const float sinv = 1.f / ssum;
#pragma unroll
    for (int o = 0; o < 8; ++o) A[o * 8 + v] = M[o] * sinv;   // S column
    wavefence();

    // ---- W row (packed): W = adj * (S + edge) ----
    const float4* sr = (const float4*)(A + v * 8);
    const float4 s0 = sr[0], s1 = sr[1];
    v2f W2[4];
    W2[0] = mkv(a0.x, a0.y) * (mkv(s0.x, s0.y) + mkv(e0.x, e0.y));
    W2[1] = mkv(a0.z, a0.w) * (mkv(s0.z, s0.w) + mkv(e0.z, e0.w));
    W2[2] = mkv(a1.x, a1.y) * (mkv(s1.x, s1.y) + mkv(e1.x, e1.y));
    W2[3] = mkv(a1.z, a1.w) * (mkv(s1.z, s1.w) + mkv(e1.z, e1.w));

    // ---- layer 1: h = leaky(W @ g1 + b1), g1 consumed in two halves ----
    v2f m1[8];
#pragma unroll
    for (int p = 0; p < 8; ++p) m1[p] = mkv(0.f, 0.f);
#pragma unroll
    for (int w = 0; w < 8; ++w) {                 // half 0: g1[:,0:8]
        const float wv = (w & 1) ? W2[w >> 1].y : W2[w >> 1].x;
        const v2f f2 = mkv(wv, wv);
        const float4* gp = (const float4*)(SB + w * 8);
        const float4 q0 = gp[0], q1 = gp[1];
        m1[0] = __builtin_elementwise_fma(f2, mkv(q0.x, q0.y), m1[0]);
        m1[1] = __builtin_elementwise_fma(f2, mkv(q0.z, q0.w), m1[1]);
        m1[2] = __builtin_elementwise_fma(f2, mkv(q1.x, q1.y), m1[2]);
        m1[3] = __builtin_elementwise_fma(f2, mkv(q1.z, q1.w), m1[3]);
    }
    wavefence();                                  // half-0 reads done
    {
        float4* gp = (float4*)(SB + v * 8);       // publish half 1: g1[:,8:16]
        gp[0] = make_float4(g12[4].x, g12[4].y, g12[5].x, g12[5].y);
        gp[1] = make_float4(g12[6].x, g12[6].y, g12[7].x, g12[7].y);
    }
    wavefence();
#pragma unroll
    for (int w = 0; w < 8; ++w) {                 // half 1
        const float wv = (w & 1) ? W2[w >> 1].y : W2[w >> 1].x;
        const v2f f2 = mkv(wv, wv);
        const float4* gp = (const float4*)(SB + w * 8);
        const float4 q0 = gp[0], q1 = gp[1];
        m1[4] = __builtin_elementwise_fma(f2, mkv(q0.x, q0.y), m1[4]);
        m1[5] = __builtin_elementwise_fma(f2, mkv(q0.z, q0.w), m1[5]);
        m1[6] = __builtin_elementwise_fma(f2, mkv(q1.x, q1.y), m1[6]);
        m1[7] = __builtin_elementwise_fma(f2, mkv(q1.z, q1.w), m1[7]);
    }
    v2f h[8];
    {
        const v2f* b1p = (const v2f*)&wsW[B1O];
        const v2f k01 = mkv(0.01f, 0.01f);
#pragma unroll
        for (int p = 0; p < 8; ++p) {
            const v2f t = m1[p] + b1p[p];
            h[p] = __builtin_elementwise_max(t, t * k01);   // leaky
        }
    }

    // ---- g2 row: g2[n] = dot(h, w2[:,n]), packed over n ----
    v2f g22[4];
#pragma unroll
    for (int p = 0; p < 4; ++p) g22[p] = mkv(0.f, 0.f);
#pragma unroll
    for (int j = 0; j < 16; ++j) {
        const float hv = (j & 1) ? h[j >> 1].y : h[j >> 1].x;
        const v2f f2 = mkv(hv, hv);
        const float4* w2r = (const float4*)(wsW + W2O + j * 8);
        const float4 r0 = w2r[0], r1 = w2r[1];
        g22[0] = __builtin_elementwise_fma(f2, mkv(r0.x, r0.y), g22[0]);
        g22[1] = __builtin_elementwise_fma(f2, mkv(r0.z, r0.w), g22[1]);
        g22[2] = __builtin_elementwise_fma(f2, mkv(r1.x, r1.y), g22[2]);
        g22[3] = __builtin_elementwise_fma(f2, mkv(r1.z, r1.w), g22[3]);
    }
    wavefence();   // g1 half-1 reads done -> overwrite g-rows with g2
    {
        float4* gp = (float4*)(SB + v * 8);
        gp[0] = make_float4(g22[0].x, g22[0].y, g22[1].x, g22[1].y);
        gp[1] = make_float4(g22[2].x, g22[2].y, g22[3].x, g22[3].y);
    }
    wavefence();

    // ---- layer 2: h2 = leaky(W @ g2 + b2), packed ----
    v2f m2[4];
#pragma unroll
    for (int p = 0; p < 4; ++p) m2[p] = mkv(0.f, 0.f);
#pragma unroll
    for (int w = 0; w < 8; ++w) {
        const float wv = (w & 1) ? W2[w >> 1].y : W2[w >> 1].x;
        const v2f f2 = mkv(wv, wv);
        const float4* gp = (const float4*)(SB + w * 8);
        const float4 q0 = gp[0], q1 = gp[1];
        m2[0] = __builtin_elementwise_fma(f2, mkv(q0.x, q0.y), m2[0]);
        m2[1] = __builtin_elementwise_fma(f2, mkv(q0.z, q0.w), m2[1]);
        m2[2] = __builtin_elementwise_fma(f2, mkv(q1.x, q1.y), m2[2]);
        m2[3] = __builtin_elementwise_fma(f2, mkv(q1.z, q1.w), m2[3]);
    }
    v2f h2[4];
    {
        const v2f* b2p = (const v2f*)&wsW[B2O];
        const v2f k01 = mkv(0.01f, 0.01f);
#pragma unroll
        for (int p = 0; p < 4; ++p) {
            const v2f t = m2[p] + b2p[p];
            h2[p] = __builtin_elementwise_max(t, t * k01);
        }
    }

    // ---- gate-logit row: Y[o] = dot(h2, wg[o,:]), packed over o via wgT ----
    v2f Y2[4];
#pragma unroll
    for (int p = 0; p < 4; ++p) Y2[p] = mkv(0.f, 0.f);
#pragma unroll
    for (int n = 0; n < 8; ++n) {
        const float hv = (n & 1) ? h2[n >> 1].y : h2[n >> 1].x;
        const v2f f2 = mkv(hv, hv);
        const float4* wgr = (const float4*)(wsW + WGT + n * 8);
        const float4 r0 = wgr[0], r1 = wgr[1];
        Y2[0] = __builtin_elementwise_fma(f2, mkv(r0.x, r0.y), Y2[0]);
        Y2[1] = __builtin_elementwise_fma(f2, mkv(r0.z, r0.w), Y2[1]);
        Y2[2] = __builtin_elementwise_fma(f2, mkv(r1.x, r1.y), Y2[2]);
        Y2[3] = __builtin_elementwise_fma(f2, mkv(r1.z, r1.w), Y2[3]);
    }
    wavefence();   // g2 reads done -> overwrite with pool layout
    {
        // interleaved (Y, h2) pairs: float4 j = (Y[2j], h2[2j], Y[2j+1], h2[2j+1])
        float4* pp = (float4*)(SB + v * 16);
        pp[0] = make_float4(Y2[0].x, h2[0].x, Y2[0].y, h2[0].y);
        pp[1] = make_float4(Y2[1].x, h2[1].x, Y2[1].y, h2[1].y);
        pp[2] = make_float4(Y2[2].x, h2[2].x, Y2[2].y, h2[2].y);
        pp[3] = make_float4(Y2[3].x, h2[3].x, Y2[3].y, h2[3].y);
        SB[128 + v] = type;
    }
    wavefence();

    // ---- attention pooling: thread handles gate-row o = v.
    // bg[o] constant along softmax axis -> drops out; masked rows logit 0.
    const int o = v;
    float yc[8], hc[8], ty[8];
#pragma unroll
    for (int vp = 0; vp < 8; ++vp) {
        const float2 q = *(const float2*)(SB + vp * 16 + o * 2);
        yc[vp] = q.x;
        hc[vp] = q.y;
        ty[vp] = SB[128 + vp];
    }
    float xp = 0.f;
#pragma unroll
    for (int t = 0; t < 2; ++t) {
        const float tv = (float)t;
        float l[8];
        float lmx = -1e30f;
#pragma unroll
        for (int vp = 0; vp < 8; ++vp) {
            l[vp] = (ty[vp] == tv) ? yc[vp] : 0.f;
            lmx = fmaxf(lmx, l[vp]);
        }
        float esum = 0.f, num = 0.f;
#pragma unroll
        for (int vp = 0; vp < 8; ++vp) {
            const float e = __expf(l[vp] - lmx);
            esum += e;
            num  += (ty[vp] == tv) ? e * hc[vp] : 0.f;
        }
        xp += 0.5f * num / esum;
    }

    // ---- classifier ----
    const float y0 = grp_sum8(xp * wsW[WFO + o]);
    const float y1 = grp_sum8(xp * wsW[WFO + 8 + o]);
    if (v == 0) {
        float2* op = (float2*)(out + b * 2);
        *op = make_float2(y0 + wsW[BFO], y1 + wsW[BFO + 1]);
    }
}

extern "C" void kernel_launch(void* const* d_in, const int* in_sizes, int n_in,
                              void* d_out, int out_size, void* d_ws, size_t ws_size,
                              hipStream_t stream) {
    const float* x    = (const float*)d_in[0];
    const float* adj  = (const float*)d_in[1];
    const float* edge = (const float*)d_in[2];
    // d_in[3]=wa, d_in[4]=ba unused by the reference.
    const float* wb   = (const float*)d_in[5];
    const float* bb   = (const float*)d_in[6];
    const float* w1   = (const float*)d_in[7];
    const float* b1   = (const float*)d_in[8];
    const float* w2   = (const float*)d_in[9];
    const float* b2   = (const float*)d_in[10];
    const float* wg   = (const float*)d_in[11];
    // d_in[12]=bg drops out of the softmax (constant along the node axis).
    const float* wf   = (const float*)d_in[13];
    const float* bf   = (const float*)d_in[14];
    float* out = (float*)d_out;
    float* ws  = (float*)d_ws;

    const int Btot    = in_sizes[0] / 264;            // B = 131072
    const int nGroups = (Btot + SLOTS - 1) / SLOTS;   // 8192

    gcn_prep<<<1, 256, 0, stream>>>(wb, bb, w1, b1, w2, b2, wg, wf, bf, ws);
    gcn_fused<<<nGroups, NTHREADS, 0, stream>>>(x, adj, edge, ws, out, nGroups);
}

// Round 3
// 273.236 us; speedup vs baseline: 1.1071x; 1.0073x over previous
//
#include <hip/hip_runtime.h>

// GCN_84499186582104 — fully fused, one thread per (batch, node).
// B=131072, V=8, NFEAT=32, NHID1=16, NHID12=8, NCLASS=2.
// R10 (base = R9, 85us kernel / 275us JSON):
//   Post-mortem R9: spills fixed (WRITE 29.7->1MB), L3 reuse back
//   (FETCH 205->105MB), kernel 115->85us. BUT (a) occupancy stuck at
//   ~36% (≈6 blocks/CU) for both 8-block-static (R7) and 16-block-static
//   (R9) configs -> evidence of a per-CU workgroup-slot cap, not a
//   VGPR/LDS/thread limit; (b) the serialized gcn_prep launch costs
//   ~15us of graded time (R9 kernel -11us vs R7 but JSON +4us).
//   Changes:
//   - Prep kernel ELIMINATED. Fk/Y loops restructured to consume natural
//     wb/wg layouts (pair FMAs over the input index, per-o v2f
//     accumulators, one hadd at the end). All weight reads are uniform
//     compile-time offsets off kernel args -> s_load on the scalar pipe
//     (same cost class as the d_ws reads), no transposes needed.
//     w1/w2/biases were already consumed in natural layout.
//   - 256-thread blocks (SLOTS=32, 4 waves/WG): per-thread code and
//     per-wave LDS region identical; if the WG-slot cap holds, resident
//     waves/CU go 12 -> ~24.
//   LDS = 4 wave regions x 1120 floats = 17920 B.

#define SLOTS 32      // batches per block
#define NTHREADS 256  // 8 threads per batch; slots never span a wave

typedef float v2f __attribute__((ext_vector_type(2)));
typedef float4 __attribute__((aligned(4))) f4u;   // dword-aligned float4 load

__device__ __forceinline__ float grp_sum8(float x) {
    x += __shfl_xor(x, 1);
    x += __shfl_xor(x, 2);
    x += __shfl_xor(x, 4);
    return x;
}
__device__ __forceinline__ void wavefence() { __builtin_amdgcn_wave_barrier(); }
__device__ __forceinline__ v2f mkv(float a, float b) { v2f r; r.x = a; r.y = b; return r; }

// LDS float layout (per-wave region of 1120 floats; slot stride 140):
//   SB = lds + (slot>>3)*1120 + sl*140, sl = slot&7
//   xstage cells:  SB + n*16 + ((c + (n>>1) + sl)&3)*4  (phase-local chunk c)
//   A (Fk/S):      SB + 64 + o*8 + w
//   g-rows:        SB + r*8            (g1 halves, then g2)
//   pool:          SB + vp*16 + o*2 (Y), +1 (h2);  type at SB + 128 + vp

// One K-step of the fused Fk/g1 loop: kk = phase-local chunk (0..3),
// cb = global feature base for this chunk. Fk pairs over c (natural wb
// rows, SGPR pairs); g1 pairs over j (natural w1 rows, SGPR pairs).
#define KSTEP(kk, cb) { \
    const float4 qk = *(const float4*)(SB + v * 16 + ((((kk) + (v >> 1) + sl) & 3) << 2)); \
    const v2f fA = mkv(qk.x, qk.y), fB = mkv(qk.z, qk.w); \
    _Pragma("unroll") \
    for (int o = 0; o < 8; ++o) { \
        Fko[o] = __builtin_elementwise_fma(fA, *(const v2f*)(wb + o * 32 + (cb)),     Fko[o]); \
        Fko[o] = __builtin_elementwise_fma(fB, *(const v2f*)(wb + o * 32 + (cb) + 2), Fko[o]); \
    } \
    const float fu[4] = { qk.x, qk.y, qk.z, qk.w }; \
    _Pragma("unroll") \
    for (int u = 0; u < 4; ++u) { \
        const int c = (cb) + u; \
        const v2f f2 = mkv(fu[u], fu[u]); \
        _Pragma("unroll") \
        for (int p = 0; p < 8; ++p) \
            g12[p] = __builtin_elementwise_fma(f2, *(const v2f*)(w1 + c * 16 + 2 * p), g12[p]); \
    } }

__global__ __launch_bounds__(NTHREADS, 4)
void gcn_fused(const float* __restrict__ x,
               const float* __restrict__ adj,
               const float* __restrict__ edge,
               const float* __restrict__ wb, const float* __restrict__ bb,
               const float* __restrict__ w1, const float* __restrict__ b1,
               const float* __restrict__ w2, const float* __restrict__ b2,
               const float* __restrict__ wg,
               const float* __restrict__ wf, const float* __restrict__ bf,
               float* __restrict__ out, int nGroups)
{
    __shared__ __align__(16) float lds[4480];   // 17920 B

    const int tid  = threadIdx.x;
    const int slot = tid >> 3;
    const int v    = tid & 7;
    const int sl   = slot & 7;
    float* SB = &lds[(slot >> 3) * 1120 + sl * 140];
    float* A  = SB + 64;

    long long bb_ = (long long)blockIdx.x * SLOTS + slot;
    if (bb_ >= (long long)nGroups * SLOTS) bb_ = (long long)nGroups * SLOTS - 1;
    const size_t b = (size_t)bb_;

    // ---- global loads: phase-A x first, then adj/edge/type (stay in flight) ----
    const float* xb = x + b * 264;
    const int nb = v & 4;           // this lane covers nodes nb..nb+3
    const int cl = v & 3;           // ... feature chunk cl of each
    float4 xa[4];
#pragma unroll
    for (int i = 0; i < 4; ++i)
        xa[i] = *(const f4u*)(xb + (nb + i) * 33 + 1 + cl * 4);

    const float4* ar = (const float4*)(adj  + b * 64 + (size_t)v * 8);
    const float4* er = (const float4*)(edge + b * 64 + (size_t)v * 8);
    const float4 a0 = ar[0], a1 = ar[1];
    const float4 e0 = er[0], e1 = er[1];
    const float type = xb[v * 33];

    // ---- stage phase A (features 0..15 of all 8 nodes), issue phase-B loads ----
#pragma unroll
    for (int i = 0; i < 4; ++i) {
        const int n = nb + i;
        *(float4*)(SB + n * 16 + (((cl + (n >> 1) + sl) & 3) << 2)) = xa[i];
    }
    float4 xc[4];
#pragma unroll
    for (int i = 0; i < 4; ++i)
        xc[i] = *(const f4u*)(xb + (nb + i) * 33 + 17 + cl * 4);
    wavefence();

    // ---- Fk (per-o, paired over c) + g1 (paired over j), packed fp32 ----
    v2f Fko[8];
#pragma unroll
    for (int o = 0; o < 8; ++o) Fko[o] = mkv(0.f, 0.f);
    v2f g12[8];
#pragma unroll
    for (int p = 0; p < 8; ++p) g12[p] = mkv(0.f, 0.f);

    KSTEP(0, 0) KSTEP(1, 4) KSTEP(2, 8) KSTEP(3, 12)
    wavefence();                    // phase-A reads done -> restage same cells
#pragma unroll
    for (int i = 0; i < 4; ++i) {
        const int n = nb + i;
        *(float4*)(SB + n * 16 + (((cl + (n >> 1) + sl) & 3) << 2)) = xc[i];
    }
    wavefence();
    KSTEP(0, 16) KSTEP(1, 20) KSTEP(2, 24) KSTEP(3, 28)
    wavefence();                    // stage dead -> A / g-rows may overwrite

    // ---- finalize Fk column: hadd + bias ----
    float Fks[8];
#pragma unroll
    for (int o = 0; o < 8; ++o) Fks[o] = Fko[o].x + Fko[o].y + bb[o];

    // ---- share Fk (column v -> A) and g1 half 0 (row v -> g-rows) ----
#pragma unroll
    for (int o = 0; o < 8; ++o) A[o * 8 + v] = Fks[o];
    {
        float4* gp = (float4*)(SB + v * 8);
        gp[0] = make_float4(g12[0].x, g12[0].y, g12[1].x, g12[1].y);
        gp[1] = make_float4(g12[2].x, g12[2].y, g12[3].x, g12[3].y);
    }
    wavefence();

    // own column as pairs over m (for the M-loop dot products)
    v2f Fk2[4];
#pragma unroll
    for (int p = 0; p < 4; ++p) Fk2[p] = mkv(Fks[2 * p], Fks[2 * p + 1]);

    // ---- M[o][v] = dot(Fk row o, Fk column v); softmax over o ----
    float M[8];
#pragma unroll
    for (int o = 0; o < 8; ++o) {
        const float4* fr = (const float4*)(A + o * 8);
        const float4 r0 = fr[0], r1 = fr[1];
        v2f acc = mkv(0.f, 0.f);
        acc = __builtin_elementwise_fma(mkv(r0.x, r0.y), Fk2[0], acc);
        acc = __builtin_elementwise_fma(mkv(r0.z, r0.w), Fk2[1], acc);
        acc = __builtin_elementwise_fma(mkv(r1.x, r1.y), Fk2[2], acc);
        acc = __builtin_elementwise_fma(mkv(r1.z, r1.w), Fk2[3], acc);
        M[o] = acc.x + acc.y;
    }
    wavefence();
    float mx = M[0];
#pragma unroll
    for (int o = 1; o < 8; ++o) mx = fmaxf(mx, M[o]);
    float ssum = 0.f;
#pragma unroll
    for (int o = 0; o < 8; ++o) { M[o] = __expf(M[o] - mx); ssum += M[o]; }
    const float sinv = 1.f / ssum;
#pragma unroll
    for (int o = 0; o < 8; ++o) A[o * 8 + v] = M[o] * sinv;   // S column
    wavefence();

    // ---- W row (packed): W = adj * (S + edge) ----
    const float4* sr = (const float4*)(A + v * 8);
    const float4 s0 = sr[0], s1 = sr[1];
    v2f W2[4];
    W2[0] = mkv(a0.x, a0.y) * (mkv(s0.x, s0.y) + mkv(e0.x, e0.y));
    W2[1] = mkv(a0.z, a0.w) * (mkv(s0.z, s0.w) + mkv(e0.z, e0.w));
    W2[2] = mkv(a1.x, a1.y) * (mkv(s1.x, s1.y) + mkv(e1.x, e1.y));
    W2[3] = mkv(a1.z, a1.w) * (mkv(s1.z, s1.w) + mkv(e1.z, e1.w));

    // ---- layer 1: h = leaky(W @ g1 + b1), g1 consumed in two halves ----
    v2f m1[8];
#pragma unroll
    for (int p = 0; p < 8; ++p) m1[p] = mkv(0.f, 0.f);
#pragma unroll
    for (int w = 0; w < 8; ++w) {                 // half 0: g1[:,0:8]
        const float wv = (w & 1) ? W2[w >> 1].y : W2[w >> 1].x;
        const v2f f2 = mkv(wv, wv);
        const float4* gp = (const float4*)(SB + w * 8);
        const float4 q0 = gp[0], q1 = gp[1];
        m1[0] = __builtin_elementwise_fma(f2, mkv(q0.x, q0.y), m1[0]);
        m1[1] = __builtin_elementwise_fma(f2, mkv(q0.z, q0.w), m1[1]);
        m1[2] = __builtin_elementwise_fma(f2, mkv(q1.x, q1.y), m1[2]);
        m1[3] = __builtin_elementwise_fma(f2, mkv(q1.z, q1.w), m1[3]);
    }
    wavefence();                                  // half-0 reads done
    {
        float4* gp = (float4*)(SB + v * 8);       // publish half 1: g1[:,8:16]
        gp[0] = make_float4(g12[4].x, g12[4].y, g12[5].x, g12[5].y);
        gp[1] = make_float4(g12[6].x, g12[6].y, g12[7].x, g12[7].y);
    }
    wavefence();
#pragma unroll
    for (int w = 0; w < 8; ++w) {                 // half 1
        const float wv = (w & 1) ? W2[w >> 1].y : W2[w >> 1].x;
        const v2f f2 = mkv(wv, wv);
        const float4* gp = (const float4*)(SB + w * 8);
        const float4 q0 = gp[0], q1 = gp[1];
        m1[4] = __builtin_elementwise_fma(f2, mkv(q0.x, q0.y), m1[4]);
        m1[5] = __builtin_elementwise_fma(f2, mkv(q0.z, q0.w), m1[5]);
        m1[6] = __builtin_elementwise_fma(f2, mkv(q1.x, q1.y), m1[6]);
        m1[7] = __builtin_elementwise_fma(f2, mkv(q1.z, q1.w), m1[7]);
    }
    v2f h[8];
    {
        const v2f k01 = mkv(0.01f, 0.01f);
#pragma unroll
        for (int p = 0; p < 8; ++p) {
            const v2f t = m1[p] + *(const v2f*)(b1 + 2 * p);
            h[p] = __builtin_elementwise_max(t, t * k01);   // leaky
        }
    }

    // ---- g2 row: g2[n] = dot(h, w2[:,n]), packed over n (natural w2) ----
    v2f g22[4];
#pragma unroll
    for (int p = 0; p < 4; ++p) g22[p] = mkv(0.f, 0.f);
#pragma unroll
    for (int j = 0; j < 16; ++j) {
        const float hv = (j & 1) ? h[j >> 1].y : h[j >> 1].x;
        const v2f f2 = mkv(hv, hv);
#pragma unroll
        for (int p = 0; p < 4; ++p)
            g22[p] = __builtin_elementwise_fma(f2, *(const v2f*)(w2 + j * 8 + 2 * p), g22[p]);
    }
    wavefence();   // g1 half-1 reads done -> overwrite g-rows with g2
    {
        float4* gp = (float4*)(SB + v * 8);
        gp[0] = make_float4(g22[0].x, g22[0].y, g22[1].x, g22[1].y);
        gp[1] = make_float4(g22[2].x, g22[2].y, g22[3].x, g22[3].y);
    }
    wavefence();

    // ---- layer 2: h2 = leaky(W @ g2 + b2), packed ----
    v2f m2[4];
#pragma unroll
    for (int p = 0; p < 4; ++p) m2[p] = mkv(0.f, 0.f);
#pragma unroll
    for (int w = 0; w < 8; ++w) {
        const float wv = (w & 1) ? W2[w >> 1].y : W2[w >> 1].x;
        const v2f f2 = mkv(wv, wv);
        const float4* gp = (const float4*)(SB + w * 8);
        const float4 q0 = gp[0], q1 = gp[1];
        m2[0] = __builtin_elementwise_fma(f2, mkv(q0.x, q0.y), m2[0]);
        m2[1] = __builtin_elementwise_fma(f2, mkv(q0.z, q0.w), m2[1]);
        m2[2] = __builtin_elementwise_fma(f2, mkv(q1.x, q1.y), m2[2]);
        m2[3] = __builtin_elementwise_fma(f2, mkv(q1.z, q1.w), m2[3]);
    }
    v2f h2[4];
    {
        const v2f k01 = mkv(0.01f, 0.01f);
#pragma unroll
        for (int p = 0; p < 4; ++p) {
            const v2f t = m2[p] + *(const v2f*)(b2 + 2 * p);
            h2[p] = __builtin_elementwise_max(t, t * k01);
        }
    }

    // ---- gate logits: Y[o] = dot(h2, wg[o,:]) (natural wg rows, paired n) ----
    float Ys[8];
#pragma unroll
    for (int o = 0; o < 8; ++o) {
        v2f acc = mkv(0.f, 0.f);
#pragma unroll
        for (int p = 0; p < 4; ++p)
            acc = __builtin_elementwise_fma(h2[p], *(const v2f*)(wg + o * 8 + 2 * p), acc);
        Ys[o] = acc.x + acc.y;
    }
    wavefence();   // g2 reads done -> overwrite with pool layout
    {
        // interleaved (Y, h2) pairs: float4 j = (Y[2j], h2[2j], Y[2j+1], h2[2j+1])
        float4* pp = (float4*)(SB + v * 16);
        pp[0] = make_float4(Ys[0], h2[0].x, Ys[1], h2[0].y);
        pp[1] = make_float4(Ys[2], h2[1].x, Ys[3], h2[1].y);
        pp[2] = make_float4(Ys[4], h2[2].x, Ys[5], h2[2].y);
        pp[3] = make_float4(Ys[6], h2[3].x, Ys[7], h2[3].y);
        SB[128 + v] = type;
    }
    wavefence();

    // ---- attention pooling: thread handles gate-row o = v.
    // bg[o] constant along softmax axis -> drops out; masked rows logit 0.
    const int o = v;
    float yc[8], hc[8], ty[8];
#pragma unroll
    for (int vp = 0; vp < 8; ++vp) {
        const float2 q = *(const float2*)(SB + vp * 16 + o * 2);
        yc[vp] = q.x;
        hc[vp] = q.y;
        ty[vp] = SB[128 + vp];
    }
    float xp = 0.f;
#pragma unroll
    for (int t = 0; t < 2; ++t) {
        const float tv = (float)t;
        float l[8];
        float lmx = -1e30f;
#pragma unroll
        for (int vp = 0; vp < 8; ++vp) {
            l[vp] = (ty[vp] == tv) ? yc[vp] : 0.f;
            lmx = fmaxf(lmx, l[vp]);
        }
        float esum = 0.f, num = 0.f;
#pragma unroll
        for (int vp = 0; vp < 8; ++vp) {
            const float e = __expf(l[vp] - lmx);
            esum += e;
            num  += (ty[vp] == tv) ? e * hc[vp] : 0.f;
        }
        xp += 0.5f * num / esum;
    }

    // ---- classifier ----
    const float y0 = grp_sum8(xp * wf[0 * 8 + o]);
    const float y1 = grp_sum8(xp * wf[1 * 8 + o]);
    if (v == 0) {
        float2* op = (float2*)(out + b * 2);
        *op = make_float2(y0 + bf[0], y1 + bf[1]);
    }
}

extern "C" void kernel_launch(void* const* d_in, const int* in_sizes, int n_in,
                              void* d_out, int out_size, void* d_ws, size_t ws_size,
                              hipStream_t stream) {
    const float* x    = (const float*)d_in[0];
    const float* adj  = (const float*)d_in[1];
    const float* edge = (const float*)d_in[2];
    // d_in[3]=wa, d_in[4]=ba unused by the reference.
    const float* wb   = (const float*)d_in[5];
    const float* bb   = (const float*)d_in[6];
    const float* w1   = (const float*)d_in[7];
    const float* b1   = (const float*)d_in[8];
    const float* w2   = (const float*)d_in[9];
    const float* b2   = (const float*)d_in[10];
    const float* wg   = (const float*)d_in[11];
    // d_in[12]=bg drops out of the softmax (constant along the node axis).
    const float* wf   = (const float*)d_in[13];
    const float* bf   = (const float*)d_in[14];
    float* out = (float*)d_out;

    const int Btot    = in_sizes[0] / 264;            // B = 131072
    const int nGroups = (Btot + SLOTS - 1) / SLOTS;   // 4096

    gcn_fused<<<nGroups, NTHREADS, 0, stream>>>(x, adj, edge, wb, bb, w1, b1,
                                                w2, b2, wg, wf, bf, out, nGroups);
}